// Round 2
// baseline (1823.050 us; speedup 1.0000x reference)
//
#include <hip/hip_runtime.h>
#include <hip/hip_bf16.h>

typedef __bf16 bf16_t;
typedef __bf16 bfrag __attribute__((ext_vector_type(8)));
typedef float f4 __attribute__((ext_vector_type(4)));

#define S_LEN 2048
#define HQ_N 32
#define HK_N 8
#define D_DIM 64

// ---------------------------------------------------------------------------
// Tiled MFMA GEMM: C[M,N](fp32) = A[M,K] * B[K,N](fp32), row-major.
// A is fp32 or bf16 (template); both operands converted to bf16 in LDS,
// MFMA bf16 with fp32 accumulate. Block 256 = 4 waves; tile 128x128, BK=32.
// ---------------------------------------------------------------------------
template<bool A_IS_BF16>
__global__ __launch_bounds__(256) void gemm_nn(
    const void* __restrict__ Av, const float* __restrict__ B,
    float* __restrict__ C, int M, int N, int K)
{
    __shared__ bf16_t As[128][40];   // pad 8: 16B-aligned rows
    __shared__ bf16_t Bs[32][130];   // pad 2: conflict-free u16 b-frag reads
    const int tid  = threadIdx.x;
    const int wave = tid >> 6;
    const int lane = tid & 63;
    const int lrow = lane & 15;
    const int lq   = lane >> 4;
    const int wm   = (wave >> 1) * 64;
    const int wn   = (wave & 1) * 64;
    const int bm   = blockIdx.y * 128;
    const int bn   = blockIdx.x * 128;

    f4 acc[4][4];
#pragma unroll
    for (int i = 0; i < 4; ++i)
#pragma unroll
        for (int j = 0; j < 4; ++j)
            acc[i][j] = (f4){0.f, 0.f, 0.f, 0.f};

    const int ar  = tid >> 2;         // 0..63  (A stage row)
    const int ac  = (tid & 3) * 8;    // 0,8,16,24
    const int bk  = tid >> 3;         // 0..31  (B stage k)
    const int bn0 = (tid & 7) * 16;   // 0..112

    const bf16_t* Ab = (const bf16_t*)Av;
    const float*  Af = (const float*)Av;

    for (int k0 = 0; k0 < K; k0 += 32) {
        // ---- global loads into registers (coalesced) ----
        bfrag a0, a1;
        if (A_IS_BF16) {
            a0 = *(const bfrag*)(Ab + (size_t)(bm + ar) * K + k0 + ac);
            a1 = *(const bfrag*)(Ab + (size_t)(bm + ar + 64) * K + k0 + ac);
        } else {
            const float* p0 = Af + (size_t)(bm + ar) * K + k0 + ac;
            const float* p1 = Af + (size_t)(bm + ar + 64) * K + k0 + ac;
            float t0[8], t1[8];
            *(f4*)&t0[0] = *(const f4*)(p0);
            *(f4*)&t0[4] = *(const f4*)(p0 + 4);
            *(f4*)&t1[0] = *(const f4*)(p1);
            *(f4*)&t1[4] = *(const f4*)(p1 + 4);
#pragma unroll
            for (int i = 0; i < 8; ++i) { a0[i] = (bf16_t)t0[i]; a1[i] = (bf16_t)t1[i]; }
        }
        bf16_t bb[16];
        {
            const float* pb = B + (size_t)(k0 + bk) * N + bn + bn0;
            float tb[16];
#pragma unroll
            for (int i = 0; i < 4; ++i) *(f4*)&tb[4 * i] = *(const f4*)(pb + 4 * i);
#pragma unroll
            for (int i = 0; i < 16; ++i) bb[i] = (bf16_t)tb[i];
        }

        __syncthreads();   // previous iter's LDS reads complete
        *(bfrag*)(&As[ar][ac])      = a0;
        *(bfrag*)(&As[ar + 64][ac]) = a1;
        {   // Bs rows are 260B (4B-aligned only) -> 4B stores, 2-way banks (free)
            const unsigned int* w = (const unsigned int*)bb;
#pragma unroll
            for (int i = 0; i < 8; ++i)
                *(unsigned int*)(&Bs[bk][bn0 + 2 * i]) = w[i];
        }
        __syncthreads();

        bfrag aF[4], bF[4];
#pragma unroll
        for (int i = 0; i < 4; ++i)
            aF[i] = *(const bfrag*)(&As[wm + i * 16 + lrow][lq * 8]);
#pragma unroll
        for (int j = 0; j < 4; ++j) {
            bfrag t;
#pragma unroll
            for (int jj = 0; jj < 8; ++jj)
                t[jj] = Bs[lq * 8 + jj][wn + j * 16 + lrow];
            bF[j] = t;
        }
#pragma unroll
        for (int i = 0; i < 4; ++i)
#pragma unroll
            for (int j = 0; j < 4; ++j)
                acc[i][j] = __builtin_amdgcn_mfma_f32_16x16x32_bf16(
                    aF[i], bF[j], acc[i][j], 0, 0, 0);
    }

    // epilogue: C/D layout col=lane&15, row=(lane>>4)*4+reg  [m89/m91 verified]
#pragma unroll
    for (int i = 0; i < 4; ++i)
#pragma unroll
        for (int j = 0; j < 4; ++j)
#pragma unroll
            for (int r = 0; r < 4; ++r) {
                int row = bm + wm + i * 16 + lq * 4 + r;
                int col = bn + wn + j * 16 + lrow;
                C[(size_t)row * N + col] = acc[i][j][r];
            }
}

// ---------------------------------------------------------------------------
// In-place RoPE on t[B,S,H,64] fp32: halves (d, d+32) rotated by cos/sin[s,d].
// ---------------------------------------------------------------------------
__global__ __launch_bounds__(256) void rope_kernel(
    float* __restrict__ t, const float* __restrict__ cs,
    const float* __restrict__ sn, int h_shift, int total)
{
    int idx = blockIdx.x * 256 + threadIdx.x;
    if (idx >= total) return;
    int d1   = idx & 31;
    int rest = idx >> 5;                       // (b*S+s)*H + h
    int s    = (rest >> h_shift) & (S_LEN - 1);
    size_t base = (size_t)rest * 64;
    float t1 = t[base + d1];
    float t2 = t[base + d1 + 32];
    float c  = cs[s * 32 + d1];
    float s_ = sn[s * 32 + d1];
    t[base + d1]      = t1 * c - t2 * s_;
    t[base + d1 + 32] = t2 * c + t1 * s_;
}

// ---------------------------------------------------------------------------
// Flash-style attention (NO 1/sqrt(d) scale, additive mask), GQA G=4.
// fp32 q/k/v/mask in, bf16 o out. Block 256 = 16x16 (ty,tx); one
// (b, h, 64-row Q tile) per block; 64-key tiles; 4x4 register blocking;
// online softmax with 16-lane shuffle reductions; P staged over K's LDS.
// ---------------------------------------------------------------------------
__global__ __launch_bounds__(256) void attn_kernel(
    const float* __restrict__ q, const float* __restrict__ k,
    const float* __restrict__ v, const float* __restrict__ mask,
    bf16_t* __restrict__ o)
{
    __shared__ float Qs[64][65];
    __shared__ float KPs[64][65];   // K tile, reused as P tile
    __shared__ float Vs[64][65];
    const int tid = threadIdx.x;
    const int qt  = blockIdx.x;     // 0..31 (Q tile)
    const int h   = blockIdx.y;     // 0..31
    const int b   = blockIdx.z;     // 0..1
    const int hk  = h >> 2;         // GQA: G = 4
    const int ty  = tid >> 4;       // 0..15
    const int tx  = tid & 15;
    const int s0  = qt * 64;
    const int r   = tid >> 2;       // staging row 0..63
    const int c0  = (tid & 3) * 16; // staging col 0..48

    {   // stage Q tile
        const float* src = q + ((size_t)(b * S_LEN + s0 + r) * HQ_N + h) * D_DIM + c0;
#pragma unroll
        for (int i = 0; i < 4; ++i) {
            f4 t = *(const f4*)(src + 4 * i);
#pragma unroll
            for (int jj = 0; jj < 4; ++jj) Qs[r][c0 + 4 * i + jj] = t[jj];
        }
    }

    float m_i[4], l_i[4], o_acc[4][4];
#pragma unroll
    for (int i = 0; i < 4; ++i) {
        m_i[i] = -1e30f; l_i[i] = 0.f;
#pragma unroll
        for (int j = 0; j < 4; ++j) o_acc[i][j] = 0.f;
    }

    for (int kt = 0; kt < 32; ++kt) {
        const float* ksrc = k + ((size_t)(b * S_LEN + kt * 64 + r) * HK_N + hk) * D_DIM + c0;
        const float* vsrc = v + ((size_t)(b * S_LEN + kt * 64 + r) * HK_N + hk) * D_DIM + c0;
        float kreg[16], vreg[16];
#pragma unroll
        for (int i = 0; i < 4; ++i) *(f4*)&kreg[4 * i] = *(const f4*)(ksrc + 4 * i);
#pragma unroll
        for (int i = 0; i < 4; ++i) *(f4*)&vreg[4 * i] = *(const f4*)(vsrc + 4 * i);
        __syncthreads();   // previous tile's P/V reads (and Q stage) complete
#pragma unroll
        for (int i = 0; i < 16; ++i) KPs[r][c0 + i] = kreg[i];
#pragma unroll
        for (int i = 0; i < 16; ++i) Vs[r][c0 + i]  = vreg[i];
        __syncthreads();

        // scores: 4x4 per thread
        float sc[4][4] = {};
        for (int d = 0; d < 64; ++d) {
            float qv[4], kv[4];
#pragma unroll
            for (int i = 0; i < 4; ++i) qv[i] = Qs[4 * ty + i][d];
#pragma unroll
            for (int j = 0; j < 4; ++j) kv[j] = KPs[4 * tx + j][d];
#pragma unroll
            for (int i = 0; i < 4; ++i)
#pragma unroll
                for (int j = 0; j < 4; ++j)
                    sc[i][j] = fmaf(qv[i], kv[j], sc[i][j]);
        }
        // additive mask
#pragma unroll
        for (int i = 0; i < 4; ++i)
#pragma unroll
            for (int j = 0; j < 4; ++j)
                sc[i][j] += mask[(size_t)(s0 + 4 * ty + i) * S_LEN + kt * 64 + 4 * tx + j];

        // online softmax update (rows live across the 16 tx lanes of a wave)
        float p[4][4];
#pragma unroll
        for (int i = 0; i < 4; ++i) {
            float tmax = fmaxf(fmaxf(sc[i][0], sc[i][1]), fmaxf(sc[i][2], sc[i][3]));
#pragma unroll
            for (int off = 8; off >= 1; off >>= 1)
                tmax = fmaxf(tmax, __shfl_xor(tmax, off));
            float mnew  = fmaxf(m_i[i], tmax);
            float alpha = __expf(m_i[i] - mnew);
            float rs = 0.f;
#pragma unroll
            for (int j = 0; j < 4; ++j) { p[i][j] = __expf(sc[i][j] - mnew); rs += p[i][j]; }
#pragma unroll
            for (int off = 8; off >= 1; off >>= 1)
                rs += __shfl_xor(rs, off);
            l_i[i] = l_i[i] * alpha + rs;
            m_i[i] = mnew;
#pragma unroll
            for (int j = 0; j < 4; ++j) o_acc[i][j] *= alpha;
        }
        __syncthreads();   // all score-phase KPs reads complete
#pragma unroll
        for (int i = 0; i < 4; ++i)
#pragma unroll
            for (int j = 0; j < 4; ++j)
                KPs[4 * ty + i][4 * tx + j] = p[i][j];
        __syncthreads();

        // PV: o[4 rows][4 dims] += P * V over this tile's 64 keys
        for (int kk = 0; kk < 64; ++kk) {
            float pv[4], vv[4];
#pragma unroll
            for (int i = 0; i < 4; ++i) pv[i] = KPs[4 * ty + i][kk];
#pragma unroll
            for (int j = 0; j < 4; ++j) vv[j] = Vs[kk][4 * tx + j];
#pragma unroll
            for (int i = 0; i < 4; ++i)
#pragma unroll
                for (int j = 0; j < 4; ++j)
                    o_acc[i][j] = fmaf(pv[i], vv[j], o_acc[i][j]);
        }
    }

    // epilogue: o[b, s, h, d] bf16
#pragma unroll
    for (int i = 0; i < 4; ++i) {
        float inv = 1.f / l_i[i];
#pragma unroll
        for (int j = 0; j < 4; ++j) {
            size_t idx = ((size_t)(b * S_LEN + s0 + 4 * ty + i) * HQ_N + h) * D_DIM + 4 * tx + j;
            o[idx] = (bf16_t)(o_acc[i][j] * inv);
        }
    }
}

// ---------------------------------------------------------------------------
extern "C" void kernel_launch(void* const* d_in, const int* in_sizes, int n_in,
                              void* d_out, int out_size, void* d_ws, size_t ws_size,
                              hipStream_t stream)
{
    const float* x    = (const float*)d_in[0];
    const float* rc   = (const float*)d_in[1];
    const float* rs   = (const float*)d_in[2];
    const float* mask = (const float*)d_in[3];
    const float* Wq   = (const float*)d_in[4];
    const float* Wk   = (const float*)d_in[5];
    const float* Wv   = (const float*)d_in[6];
    const float* Wo   = (const float*)d_in[7];
    float* out = (float*)d_out;

    char* ws = (char*)d_ws;
    float*  qb = (float*)(ws);                    // 4096x2048 fp32 = 32 MiB
    float*  kb = (float*)(ws + (32u << 20));      // 4096x512  fp32 =  8 MiB
    float*  vb = (float*)(ws + (40u << 20));      // 4096x512  fp32 =  8 MiB
    bf16_t* ob = (bf16_t*)(ws + (48u << 20));     // 4096x2048 bf16 = 16 MiB

    const int M = 2 * S_LEN;  // 4096
    dim3 blk(256);

    gemm_nn<false><<<dim3(2048 / 128, M / 128), blk, 0, stream>>>(x, Wq, qb, M, 2048, 2048);
    gemm_nn<false><<<dim3( 512 / 128, M / 128), blk, 0, stream>>>(x, Wk, kb, M,  512, 2048);
    gemm_nn<false><<<dim3( 512 / 128, M / 128), blk, 0, stream>>>(x, Wv, vb, M,  512, 2048);

    const int tq = M * HQ_N * 32;   // 4,194,304
    const int tk = M * HK_N * 32;   // 1,048,576
    rope_kernel<<<tq / 256, blk, 0, stream>>>(qb, rc, rs, 5, tq);
    rope_kernel<<<tk / 256, blk, 0, stream>>>(kb, rc, rs, 3, tk);

    attn_kernel<<<dim3(32, 32, 2), blk, 0, stream>>>(qb, kb, vb, mask, ob);

    // out-projection: o[4096, 2048(bf16)] x Wo[2048, 2048] -> out fp32
    gemm_nn<true><<<dim3(2048 / 128, M / 128), blk, 0, stream>>>(ob, Wo, out, M, 2048, 2048);
}

// Round 3
// 729.126 us; speedup vs baseline: 2.5003x; 2.5003x over previous
//
#include <hip/hip_runtime.h>
#include <hip/hip_bf16.h>

typedef __bf16 bf16_t;
typedef __bf16 bfrag __attribute__((ext_vector_type(8)));
typedef float f4 __attribute__((ext_vector_type(4)));

#define S_LEN 2048
#define HQ_N 32
#define HK_N 8
#define D_DIM 64

// ---------------------------------------------------------------------------
// Tiled MFMA GEMM: C[M,N](fp32) = A[M,K] * B[K,N](fp32), row-major.
// A is fp32 or bf16 (template); both operands converted to bf16 in LDS,
// MFMA bf16 with fp32 accumulate. Block 256 = 4 waves; tile 128x128, BK=32.
// ---------------------------------------------------------------------------
template<bool A_IS_BF16>
__global__ __launch_bounds__(256) void gemm_nn(
    const void* __restrict__ Av, const float* __restrict__ B,
    float* __restrict__ C, int M, int N, int K)
{
    __shared__ bf16_t As[128][40];   // pad 8: 16B-aligned rows
    __shared__ bf16_t Bs[32][130];   // pad 2: conflict-free u16 b-frag reads
    const int tid  = threadIdx.x;
    const int wave = tid >> 6;
    const int lane = tid & 63;
    const int lrow = lane & 15;
    const int lq   = lane >> 4;
    const int wm   = (wave >> 1) * 64;
    const int wn   = (wave & 1) * 64;
    const int bm   = blockIdx.y * 128;
    const int bn   = blockIdx.x * 128;

    f4 acc[4][4];
#pragma unroll
    for (int i = 0; i < 4; ++i)
#pragma unroll
        for (int j = 0; j < 4; ++j)
            acc[i][j] = (f4){0.f, 0.f, 0.f, 0.f};

    const int ar  = tid >> 2;         // 0..63  (A stage row)
    const int ac  = (tid & 3) * 8;    // 0,8,16,24
    const int bk  = tid >> 3;         // 0..31  (B stage k)
    const int bn0 = (tid & 7) * 16;   // 0..112

    const bf16_t* Ab = (const bf16_t*)Av;
    const float*  Af = (const float*)Av;

    for (int k0 = 0; k0 < K; k0 += 32) {
        // ---- global loads into registers (coalesced) ----
        bfrag a0, a1;
        if (A_IS_BF16) {
            a0 = *(const bfrag*)(Ab + (size_t)(bm + ar) * K + k0 + ac);
            a1 = *(const bfrag*)(Ab + (size_t)(bm + ar + 64) * K + k0 + ac);
        } else {
            const float* p0 = Af + (size_t)(bm + ar) * K + k0 + ac;
            const float* p1 = Af + (size_t)(bm + ar + 64) * K + k0 + ac;
            float t0[8], t1[8];
            *(f4*)&t0[0] = *(const f4*)(p0);
            *(f4*)&t0[4] = *(const f4*)(p0 + 4);
            *(f4*)&t1[0] = *(const f4*)(p1);
            *(f4*)&t1[4] = *(const f4*)(p1 + 4);
#pragma unroll
            for (int i = 0; i < 8; ++i) { a0[i] = (bf16_t)t0[i]; a1[i] = (bf16_t)t1[i]; }
        }
        bf16_t bb[16];
        {
            const float* pb = B + (size_t)(k0 + bk) * N + bn + bn0;
            float tb[16];
#pragma unroll
            for (int i = 0; i < 4; ++i) *(f4*)&tb[4 * i] = *(const f4*)(pb + 4 * i);
#pragma unroll
            for (int i = 0; i < 16; ++i) bb[i] = (bf16_t)tb[i];
        }

        __syncthreads();   // previous iter's LDS reads complete
        *(bfrag*)(&As[ar][ac])      = a0;
        *(bfrag*)(&As[ar + 64][ac]) = a1;
        {   // Bs rows are 260B (4B-aligned only) -> 4B stores, 2-way banks (free)
            const unsigned int* w = (const unsigned int*)bb;
#pragma unroll
            for (int i = 0; i < 8; ++i)
                *(unsigned int*)(&Bs[bk][bn0 + 2 * i]) = w[i];
        }
        __syncthreads();

        bfrag aF[4], bF[4];
#pragma unroll
        for (int i = 0; i < 4; ++i)
            aF[i] = *(const bfrag*)(&As[wm + i * 16 + lrow][lq * 8]);
#pragma unroll
        for (int j = 0; j < 4; ++j) {
            bfrag t;
#pragma unroll
            for (int jj = 0; jj < 8; ++jj)
                t[jj] = Bs[lq * 8 + jj][wn + j * 16 + lrow];
            bF[j] = t;
        }
#pragma unroll
        for (int i = 0; i < 4; ++i)
#pragma unroll
            for (int j = 0; j < 4; ++j)
                acc[i][j] = __builtin_amdgcn_mfma_f32_16x16x32_bf16(
                    aF[i], bF[j], acc[i][j], 0, 0, 0);
    }

    // epilogue: C/D layout col=lane&15, row=(lane>>4)*4+reg
#pragma unroll
    for (int i = 0; i < 4; ++i)
#pragma unroll
        for (int j = 0; j < 4; ++j)
#pragma unroll
            for (int r = 0; r < 4; ++r) {
                int row = bm + wm + i * 16 + lq * 4 + r;
                int col = bn + wn + j * 16 + lrow;
                C[(size_t)row * N + col] = acc[i][j][r];
            }
}

// ---------------------------------------------------------------------------
// In-place RoPE on t[B,S,H,64] fp32: halves (d, d+32) rotated by cos/sin[s,d].
// ---------------------------------------------------------------------------
__global__ __launch_bounds__(256) void rope_kernel(
    float* __restrict__ t, const float* __restrict__ cs,
    const float* __restrict__ sn, int h_shift, int total)
{
    int idx = blockIdx.x * 256 + threadIdx.x;
    if (idx >= total) return;
    int d1   = idx & 31;
    int rest = idx >> 5;                       // (b*S+s)*H + h
    int s    = (rest >> h_shift) & (S_LEN - 1);
    size_t base = (size_t)rest * 64;
    float t1 = t[base + d1];
    float t2 = t[base + d1 + 32];
    float c  = cs[s * 32 + d1];
    float s_ = sn[s * 32 + d1];
    t[base + d1]      = t1 * c - t2 * s_;
    t[base + d1 + 32] = t2 * c + t1 * s_;
}

// ---------------------------------------------------------------------------
// MFMA flash attention (NO 1/sqrt(d) scale, additive mask), GQA G=4.
// fp32 q/k/v/mask in, bf16 o out.
// Block = 256 threads = 4 waves; Q-tile = 128 rows (wave owns 32 = 2 m-tiles);
// K-tiles of 64 keys. Q frags live in registers for the whole kernel.
// K staged bf16 [key][d] (b128 B-frags); V staged TRANSPOSED bf16 [d][key]
// (b128 B-frags for PV). P round-trips through wave-private LDS rows
// (C-layout -> A-layout), no extra barrier. fp32 online softmax.
// ---------------------------------------------------------------------------
__global__ __launch_bounds__(256) void attn_mfma(
    const float* __restrict__ q, const float* __restrict__ k,
    const float* __restrict__ v, const float* __restrict__ mask,
    bf16_t* __restrict__ o)
{
    __shared__ bf16_t Ks[64][72];    // [key][d]   row stride 144B (16B-aligned)
    __shared__ bf16_t Vt[64][72];    // [d][key]
    __shared__ bf16_t Ps[128][72];   // [row][key] wave-private row bands

    const int tid  = threadIdx.x;
    const int wave = tid >> 6;
    const int lane = tid & 63;
    const int lrow = lane & 15;      // MFMA m/n index
    const int quad = lane >> 4;      // MFMA k-group / C-row group
    const int qt   = blockIdx.x;     // 0..15
    const int h    = blockIdx.y;     // 0..31
    const int b    = blockIdx.z;     // 0..1
    const int hk   = h >> 2;         // GQA G=4
    const int s0   = qt * 128;
    const int wrow = wave * 32;      // wave's row band within Q-tile

    // ---- Q fragments in registers: qf[mtile][kchunk] ----
    bfrag qf[2][2];
#pragma unroll
    for (int m = 0; m < 2; ++m) {
        const float* qsrc = q + ((size_t)(b * S_LEN + s0 + wrow + m * 16 + lrow) * HQ_N + h) * D_DIM;
#pragma unroll
        for (int c = 0; c < 2; ++c) {
            float t[8];
            *(f4*)&t[0] = *(const f4*)(qsrc + c * 32 + quad * 8);
            *(f4*)&t[4] = *(const f4*)(qsrc + c * 32 + quad * 8 + 4);
            bfrag f;
#pragma unroll
            for (int i = 0; i < 8; ++i) f[i] = (bf16_t)t[i];
            qf[m][c] = f;
        }
    }

    f4 oacc[2][4];
    float m_i[2][4], l_i[2][4];
#pragma unroll
    for (int m = 0; m < 2; ++m)
#pragma unroll
        for (int r = 0; r < 4; ++r) { m_i[m][r] = -1e30f; l_i[m][r] = 0.f; }
#pragma unroll
    for (int m = 0; m < 2; ++m)
#pragma unroll
        for (int n = 0; n < 4; ++n)
            oacc[m][n] = (f4){0.f, 0.f, 0.f, 0.f};

    const int skey = tid >> 2;        // 0..63 staging key
    const int sdc  = (tid & 3) * 16;  // 0,16,32,48 staging d chunk

    for (int kt = 0; kt < 32; ++kt) {
        // ---- global prefetch of K/V tile into registers ----
        const float* ksrc = k + ((size_t)(b * S_LEN + kt * 64 + skey) * HK_N + hk) * D_DIM + sdc;
        const float* vsrc = v + ((size_t)(b * S_LEN + kt * 64 + skey) * HK_N + hk) * D_DIM + sdc;
        float kr[16], vr[16];
#pragma unroll
        for (int i = 0; i < 4; ++i) *(f4*)&kr[4 * i] = *(const f4*)(ksrc + 4 * i);
#pragma unroll
        for (int i = 0; i < 4; ++i) *(f4*)&vr[4 * i] = *(const f4*)(vsrc + 4 * i);

        __syncthreads();   // prior iteration's LDS reads complete
        {   // K: [key][d], vectorized 16B stores
            bf16_t kb16[16];
#pragma unroll
            for (int i = 0; i < 16; ++i) kb16[i] = (bf16_t)kr[i];
            *(uint4*)(&Ks[skey][sdc])     = *(uint4*)&kb16[0];
            *(uint4*)(&Ks[skey][sdc + 8]) = *(uint4*)&kb16[8];
        }
#pragma unroll
        for (int i = 0; i < 16; ++i)   // V transposed: [d][key], scalar stores
            Vt[sdc + i][skey] = (bf16_t)vr[i];
        __syncthreads();

        // ---- mask loads (issued early; L2/L3-resident) ----
        float mk[2][4][4];
#pragma unroll
        for (int m = 0; m < 2; ++m)
#pragma unroll
            for (int n = 0; n < 4; ++n)
#pragma unroll
                for (int r = 0; r < 4; ++r)
                    mk[m][n][r] = mask[(size_t)(s0 + wrow + m * 16 + quad * 4 + r) * S_LEN
                                       + kt * 64 + n * 16 + lrow];

        // ---- scores: S = Q K^T via MFMA ----
        bfrag kf[4][2];
#pragma unroll
        for (int n = 0; n < 4; ++n)
#pragma unroll
            for (int c = 0; c < 2; ++c)
                kf[n][c] = *(const bfrag*)(&Ks[n * 16 + lrow][c * 32 + quad * 8]);

        f4 sc[2][4];
#pragma unroll
        for (int m = 0; m < 2; ++m)
#pragma unroll
            for (int n = 0; n < 4; ++n) {
                f4 a = (f4){0.f, 0.f, 0.f, 0.f};
                a = __builtin_amdgcn_mfma_f32_16x16x32_bf16(qf[m][0], kf[n][0], a, 0, 0, 0);
                a = __builtin_amdgcn_mfma_f32_16x16x32_bf16(qf[m][1], kf[n][1], a, 0, 0, 0);
                sc[m][n] = a;
            }
#pragma unroll
        for (int m = 0; m < 2; ++m)
#pragma unroll
            for (int n = 0; n < 4; ++n)
#pragma unroll
                for (int r = 0; r < 4; ++r)
                    sc[m][n][r] += mk[m][n][r];

        // ---- online softmax (row = wrow + m*16 + quad*4 + r, spans 16 lanes) ----
#pragma unroll
        for (int m = 0; m < 2; ++m)
#pragma unroll
            for (int r = 0; r < 4; ++r) {
                float t = fmaxf(fmaxf(sc[m][0][r], sc[m][1][r]),
                                fmaxf(sc[m][2][r], sc[m][3][r]));
#pragma unroll
                for (int off = 8; off >= 1; off >>= 1)
                    t = fmaxf(t, __shfl_xor(t, off));
                float mnew  = fmaxf(m_i[m][r], t);
                float alpha = __expf(m_i[m][r] - mnew);
                float rs = 0.f;
#pragma unroll
                for (int n = 0; n < 4; ++n) {
                    float p = __expf(sc[m][n][r] - mnew);
                    sc[m][n][r] = p;
                    rs += p;
                }
#pragma unroll
                for (int off = 8; off >= 1; off >>= 1)
                    rs += __shfl_xor(rs, off);
                l_i[m][r] = l_i[m][r] * alpha + rs;
                m_i[m][r] = mnew;
#pragma unroll
                for (int n = 0; n < 4; ++n)
                    oacc[m][n][r] *= alpha;
            }

        // ---- P: C-layout regs -> wave-private LDS rows (bf16) ----
#pragma unroll
        for (int m = 0; m < 2; ++m)
#pragma unroll
            for (int n = 0; n < 4; ++n)
#pragma unroll
                for (int r = 0; r < 4; ++r)
                    Ps[wrow + m * 16 + quad * 4 + r][n * 16 + lrow] = (bf16_t)sc[m][n][r];
        // (wave-private rows: compiler's lgkmcnt ordering suffices, no barrier)

        // ---- O += P V via MFMA ----
        bfrag pf[2][2], vf[4][2];
#pragma unroll
        for (int m = 0; m < 2; ++m)
#pragma unroll
            for (int c = 0; c < 2; ++c)
                pf[m][c] = *(const bfrag*)(&Ps[wrow + m * 16 + lrow][c * 32 + quad * 8]);
#pragma unroll
        for (int n = 0; n < 4; ++n)
#pragma unroll
            for (int c = 0; c < 2; ++c)
                vf[n][c] = *(const bfrag*)(&Vt[n * 16 + lrow][c * 32 + quad * 8]);
#pragma unroll
        for (int m = 0; m < 2; ++m)
#pragma unroll
            for (int n = 0; n < 4; ++n) {
                oacc[m][n] = __builtin_amdgcn_mfma_f32_16x16x32_bf16(pf[m][0], vf[n][0], oacc[m][n], 0, 0, 0);
                oacc[m][n] = __builtin_amdgcn_mfma_f32_16x16x32_bf16(pf[m][1], vf[n][1], oacc[m][n], 0, 0, 0);
            }
    }

    // ---- epilogue: o[b, s, h, d] bf16 ----
#pragma unroll
    for (int m = 0; m < 2; ++m)
#pragma unroll
        for (int r = 0; r < 4; ++r) {
            float inv = 1.f / l_i[m][r];
            int row = s0 + wrow + m * 16 + quad * 4 + r;
#pragma unroll
            for (int n = 0; n < 4; ++n) {
                size_t idx = ((size_t)(b * S_LEN + row) * HQ_N + h) * D_DIM + n * 16 + lrow;
                o[idx] = (bf16_t)(oacc[m][n][r] * inv);
            }
        }
}

// ---------------------------------------------------------------------------
extern "C" void kernel_launch(void* const* d_in, const int* in_sizes, int n_in,
                              void* d_out, int out_size, void* d_ws, size_t ws_size,
                              hipStream_t stream)
{
    const float* x    = (const float*)d_in[0];
    const float* rc   = (const float*)d_in[1];
    const float* rs   = (const float*)d_in[2];
    const float* mask = (const float*)d_in[3];
    const float* Wq   = (const float*)d_in[4];
    const float* Wk   = (const float*)d_in[5];
    const float* Wv   = (const float*)d_in[6];
    const float* Wo   = (const float*)d_in[7];
    float* out = (float*)d_out;

    char* ws = (char*)d_ws;
    float*  qb = (float*)(ws);                    // 4096x2048 fp32 = 32 MiB
    float*  kb = (float*)(ws + (32u << 20));      // 4096x512  fp32 =  8 MiB
    float*  vb = (float*)(ws + (40u << 20));      // 4096x512  fp32 =  8 MiB
    bf16_t* ob = (bf16_t*)(ws + (48u << 20));     // 4096x2048 bf16 = 16 MiB

    const int M = 2 * S_LEN;  // 4096
    dim3 blk(256);

    gemm_nn<false><<<dim3(2048 / 128, M / 128), blk, 0, stream>>>(x, Wq, qb, M, 2048, 2048);
    gemm_nn<false><<<dim3( 512 / 128, M / 128), blk, 0, stream>>>(x, Wk, kb, M,  512, 2048);
    gemm_nn<false><<<dim3( 512 / 128, M / 128), blk, 0, stream>>>(x, Wv, vb, M,  512, 2048);

    const int tq = M * HQ_N * 32;   // 4,194,304
    const int tk = M * HK_N * 32;   // 1,048,576
    rope_kernel<<<tq / 256, blk, 0, stream>>>(qb, rc, rs, 5, tq);
    rope_kernel<<<tk / 256, blk, 0, stream>>>(kb, rc, rs, 3, tk);

    attn_mfma<<<dim3(16, 32, 2), blk, 0, stream>>>(qb, kb, vb, mask, ob);

    // out-projection: o[4096, 2048(bf16)] x Wo[2048, 2048] -> out fp32
    gemm_nn<true><<<dim3(2048 / 128, M / 128), blk, 0, stream>>>(ob, Wo, out, M, 2048, 2048);
}

// Round 4
// 425.100 us; speedup vs baseline: 4.2885x; 1.7152x over previous
//
#include <hip/hip_runtime.h>
#include <hip/hip_bf16.h>

typedef __bf16 bf16_t;
typedef __bf16 bfrag __attribute__((ext_vector_type(8)));
typedef float f4 __attribute__((ext_vector_type(4)));

#define S_LEN 2048
#define HQ_N 32
#define HK_N 8
#define D_DIM 64
#define LOG2E 1.4426950408889634f

// ---------------------------------------------------------------------------
// fp32 -> bf16 elementwise convert (x). 8 elems/thread.
// ---------------------------------------------------------------------------
__global__ __launch_bounds__(256) void cvt_bf16(
    const float* __restrict__ src, bf16_t* __restrict__ dst, int n)
{
    int i = (blockIdx.x * 256 + threadIdx.x) * 8;
    if (i >= n) return;
    f4 a = *(const f4*)(src + i);
    f4 b = *(const f4*)(src + i + 4);
    bf16_t o[8];
#pragma unroll
    for (int j = 0; j < 4; ++j) { o[j] = (bf16_t)a[j]; o[4 + j] = (bf16_t)b[j]; }
    *(uint4*)(dst + i) = *(uint4*)o;
}

// ---------------------------------------------------------------------------
// Transpose + cvt: src fp32 [K][N] -> dst bf16 [N][K] (dst rows at row_off).
// 32x32 LDS tiles, block (32,8). Coalesced read and write.
// ---------------------------------------------------------------------------
__global__ __launch_bounds__(256) void transpose_cvt(
    const float* __restrict__ src, bf16_t* __restrict__ dst,
    int K, int N, int row_off)
{
    __shared__ float T[32][33];
    const int n0 = blockIdx.x * 32;
    const int k0 = blockIdx.y * 32;
    const int tx = threadIdx.x;      // 0..31
    const int ty = threadIdx.y;      // 0..7
#pragma unroll
    for (int i = 0; i < 4; ++i)
        T[ty + 8 * i][tx] = src[(size_t)(k0 + ty + 8 * i) * N + n0 + tx];
    __syncthreads();
#pragma unroll
    for (int i = 0; i < 4; ++i)
        dst[(size_t)(row_off + n0 + ty + 8 * i) * K + k0 + tx] =
            (bf16_t)T[tx][ty + 8 * i];
}

// ---------------------------------------------------------------------------
// bf16 GEMM, B pre-transposed: C[M,N] = A[M,K] * Bt[N,K]^T.
// A bf16 [M][K], Bt bf16 [N][K], C bf16 or fp32 (ldc param).
// Block 256 = 4 waves; tile 128x128, BK=64; wave = 64x64 (4x4 of 16x16x32, 2 k-chunks).
// LDS stride 72 (16B-aligned rows, even bank-group spread for b128).
// ---------------------------------------------------------------------------
template<bool OUT_BF16>
__global__ __launch_bounds__(256) void gemm_bt(
    const bf16_t* __restrict__ A, const bf16_t* __restrict__ Bt,
    void* __restrict__ Cv, int M, int N, int K, int ldc)
{
    __shared__ bf16_t As[128][72];
    __shared__ bf16_t Bs[128][72];
    const int tid  = threadIdx.x;
    const int wave = tid >> 6;
    const int lane = tid & 63;
    const int lrow = lane & 15;
    const int quad = lane >> 4;
    const int wm   = (wave >> 1) * 64;
    const int wn   = (wave & 1) * 64;
    const int bm   = blockIdx.y * 128;
    const int bn   = blockIdx.x * 128;

    f4 acc[4][4];
#pragma unroll
    for (int i = 0; i < 4; ++i)
#pragma unroll
        for (int j = 0; j < 4; ++j)
            acc[i][j] = (f4){0.f, 0.f, 0.f, 0.f};

    const int sr = tid >> 2;          // 0..63 staging row
    const int sc = (tid & 3) * 16;    // 0,16,32,48 (k chunk of 16 bf16 = 32B)

    for (int k0 = 0; k0 < K; k0 += 64) {
        uint4 a0 = *(const uint4*)(A  + (size_t)(bm + sr)      * K + k0 + sc);
        uint4 a1 = *(const uint4*)(A  + (size_t)(bm + sr)      * K + k0 + sc + 8);
        uint4 a2 = *(const uint4*)(A  + (size_t)(bm + sr + 64) * K + k0 + sc);
        uint4 a3 = *(const uint4*)(A  + (size_t)(bm + sr + 64) * K + k0 + sc + 8);
        uint4 b0 = *(const uint4*)(Bt + (size_t)(bn + sr)      * K + k0 + sc);
        uint4 b1 = *(const uint4*)(Bt + (size_t)(bn + sr)      * K + k0 + sc + 8);
        uint4 b2 = *(const uint4*)(Bt + (size_t)(bn + sr + 64) * K + k0 + sc);
        uint4 b3 = *(const uint4*)(Bt + (size_t)(bn + sr + 64) * K + k0 + sc + 8);
        __syncthreads();
        *(uint4*)(&As[sr][sc])          = a0;
        *(uint4*)(&As[sr][sc + 8])      = a1;
        *(uint4*)(&As[sr + 64][sc])     = a2;
        *(uint4*)(&As[sr + 64][sc + 8]) = a3;
        *(uint4*)(&Bs[sr][sc])          = b0;
        *(uint4*)(&Bs[sr][sc + 8])      = b1;
        *(uint4*)(&Bs[sr + 64][sc])     = b2;
        *(uint4*)(&Bs[sr + 64][sc + 8]) = b3;
        __syncthreads();

#pragma unroll
        for (int kc = 0; kc < 2; ++kc) {
            bfrag aF[4], bF[4];
#pragma unroll
            for (int i = 0; i < 4; ++i)
                aF[i] = *(const bfrag*)(&As[wm + i * 16 + lrow][kc * 32 + quad * 8]);
#pragma unroll
            for (int j = 0; j < 4; ++j)
                bF[j] = *(const bfrag*)(&Bs[wn + j * 16 + lrow][kc * 32 + quad * 8]);
#pragma unroll
            for (int i = 0; i < 4; ++i)
#pragma unroll
                for (int j = 0; j < 4; ++j)
                    acc[i][j] = __builtin_amdgcn_mfma_f32_16x16x32_bf16(
                        aF[i], bF[j], acc[i][j], 0, 0, 0);
        }
    }

    // C/D layout: col=lane&15, row=(lane>>4)*4+reg
#pragma unroll
    for (int i = 0; i < 4; ++i)
#pragma unroll
        for (int j = 0; j < 4; ++j)
#pragma unroll
            for (int r = 0; r < 4; ++r) {
                int row = bm + wm + i * 16 + quad * 4 + r;
                int col = bn + wn + j * 16 + lrow;
                if (OUT_BF16)
                    ((bf16_t*)Cv)[(size_t)row * ldc + col] = (bf16_t)acc[i][j][r];
                else
                    ((float*)Cv)[(size_t)row * ldc + col] = acc[i][j][r];
            }
}

// ---------------------------------------------------------------------------
// RoPE in-place on fused qkv bf16 [4096][3072]: q = cols h*64+d (h<32),
// k = cols 2048 + hk*64 + d. q additionally scaled by LOG2E (for exp2 softmax).
// One thread per (row, half-dim pair). fp32 math.
// ---------------------------------------------------------------------------
__global__ __launch_bounds__(256) void rope_fused(
    bf16_t* __restrict__ t, const float* __restrict__ cs,
    const float* __restrict__ sn)
{
    int idx = blockIdx.x * 256 + threadIdx.x;   // row-major over [4096][1280]
    int cidx = idx % 1280;
    int row  = idx / 1280;
    int s    = row & (S_LEN - 1);
    int col, d1;
    float scale;
    if (cidx < 1024) {            // q: head h = cidx>>5
        d1 = cidx & 31;
        col = (cidx >> 5) * 64 + d1;
        scale = LOG2E;
    } else {                      // k: head hk = (cidx-1024)>>5
        int c2 = cidx - 1024;
        d1 = c2 & 31;
        col = 2048 + (c2 >> 5) * 64 + d1;
        scale = 1.0f;
    }
    size_t base = (size_t)row * 3072 + col;
    float t1 = (float)t[base];
    float t2 = (float)t[base + 32];
    float c  = cs[s * 32 + d1];
    float s_ = sn[s * 32 + d1];
    t[base]      = (bf16_t)((t1 * c - t2 * s_) * scale);
    t[base + 32] = (bf16_t)((t2 * c + t1 * s_) * scale);
}

// ---------------------------------------------------------------------------
// MFMA flash attention, no-max softmax (safe: scores << 88/LOG2E; bf16/fp32
// share exponent range). q pre-scaled by LOG2E -> p = exp2(s + m*LOG2E).
// l accumulated via extra PV MFMA against a register-built ones B-fragment.
// qkv fused bf16 [4096][3072]; out ob bf16 [4096][2048] (col = h*64+d).
// Block 256 = 4 waves; Q-tile 128 rows (wave = 32); K-tiles of 64 keys.
// ---------------------------------------------------------------------------
__global__ __launch_bounds__(256) void attn_mfma(
    const bf16_t* __restrict__ qkv, const float* __restrict__ mask,
    bf16_t* __restrict__ o)
{
    __shared__ bf16_t Ks[64][72];    // [key][d]
    __shared__ bf16_t Vt[64][72];    // [d][key]
    __shared__ bf16_t Ps[128][72];   // [row][key], wave-private bands

    const int tid  = threadIdx.x;
    const int wave = tid >> 6;
    const int lane = tid & 63;
    const int lrow = lane & 15;
    const int quad = lane >> 4;
    const int qt   = blockIdx.x;     // 0..15
    const int h    = blockIdx.y;     // 0..31
    const int b    = blockIdx.z;     // 0..1
    const int hk   = h >> 2;
    const int s0   = qt * 128;
    const int wrow = wave * 32;

    // ones B-fragment: B[n][k] = (n==0) -> frag[j] = (lrow==0)
    bfrag vOnes;
#pragma unroll
    for (int j = 0; j < 8; ++j) vOnes[j] = (lrow == 0) ? (bf16_t)1.0f : (bf16_t)0.0f;

    // Q fragments (bf16 direct, already *LOG2E)
    bfrag qf[2][2];
#pragma unroll
    for (int m = 0; m < 2; ++m) {
        const bf16_t* qsrc = qkv + (size_t)(b * S_LEN + s0 + wrow + m * 16 + lrow) * 3072 + h * 64;
#pragma unroll
        for (int c = 0; c < 2; ++c)
            qf[m][c] = *(const bfrag*)(qsrc + c * 32 + quad * 8);
    }

    f4 oacc[2][4], lacc[2];
#pragma unroll
    for (int m = 0; m < 2; ++m) {
        lacc[m] = (f4){0.f, 0.f, 0.f, 0.f};
#pragma unroll
        for (int n = 0; n < 4; ++n) oacc[m][n] = (f4){0.f, 0.f, 0.f, 0.f};
    }

    const int skey = tid >> 2;        // K staging: key 0..63
    const int sdc  = (tid & 3) * 16;  // d chunk
    const int vg   = tid >> 5;        // V staging: key octet 0..7
    const int vp   = tid & 31;        // d pair 0..31

    for (int kt = 0; kt < 32; ++kt) {
        // ---- global prefetch ----
        const bf16_t* ksrc = qkv + (size_t)(b * S_LEN + kt * 64 + skey) * 3072 + 2048 + hk * 64 + sdc;
        uint4 k0 = *(const uint4*)(ksrc);
        uint4 k1 = *(const uint4*)(ksrc + 8);
        unsigned int vw[8];
#pragma unroll
        for (int kk = 0; kk < 8; ++kk)
            vw[kk] = *(const unsigned int*)(qkv + (size_t)(b * S_LEN + kt * 64 + vg * 8 + kk) * 3072
                                            + 2560 + hk * 64 + 2 * vp);
        __syncthreads();   // prior iteration's LDS reads complete
        *(uint4*)(&Ks[skey][sdc])     = k0;
        *(uint4*)(&Ks[skey][sdc + 8]) = k1;
        {   // V transpose: lane holds 8 keys x 2 dims -> 2 b128 row-writes
            unsigned short lo[8], hi[8];
#pragma unroll
            for (int kk = 0; kk < 8; ++kk) { lo[kk] = vw[kk] & 0xffff; hi[kk] = vw[kk] >> 16; }
            *(uint4*)(&Vt[2 * vp][vg * 8])     = *(uint4*)lo;
            *(uint4*)(&Vt[2 * vp + 1][vg * 8]) = *(uint4*)hi;
        }
        __syncthreads();

        // ---- mask prefetch (scalar; L2/L3-resident) ----
        float mk[2][4][4];
#pragma unroll
        for (int m = 0; m < 2; ++m)
#pragma unroll
            for (int n = 0; n < 4; ++n)
#pragma unroll
                for (int r = 0; r < 4; ++r)
                    mk[m][n][r] = mask[(size_t)(s0 + wrow + m * 16 + quad * 4 + r) * S_LEN
                                       + kt * 64 + n * 16 + lrow];

        // ---- S = Q K^T (already *LOG2E) ----
        bfrag kf[4][2];
#pragma unroll
        for (int n = 0; n < 4; ++n)
#pragma unroll
            for (int c = 0; c < 2; ++c)
                kf[n][c] = *(const bfrag*)(&Ks[n * 16 + lrow][c * 32 + quad * 8]);

        f4 sc[2][4];
#pragma unroll
        for (int m = 0; m < 2; ++m)
#pragma unroll
            for (int n = 0; n < 4; ++n) {
                f4 a = (f4){0.f, 0.f, 0.f, 0.f};
                a = __builtin_amdgcn_mfma_f32_16x16x32_bf16(qf[m][0], kf[n][0], a, 0, 0, 0);
                a = __builtin_amdgcn_mfma_f32_16x16x32_bf16(qf[m][1], kf[n][1], a, 0, 0, 0);
                sc[m][n] = a;
            }

        // ---- p = exp2(s + mask*LOG2E); write P (bf16, wave-private rows) ----
#pragma unroll
        for (int m = 0; m < 2; ++m)
#pragma unroll
            for (int n = 0; n < 4; ++n)
#pragma unroll
                for (int r = 0; r < 4; ++r) {
                    float p = exp2f(fmaf(mk[m][n][r], LOG2E, sc[m][n][r]));
                    Ps[wrow + m * 16 + quad * 4 + r][n * 16 + lrow] = (bf16_t)p;
                }
        // wave-private rows: compiler lgkmcnt ordering suffices, no barrier

        // ---- O += P V ; l += P 1 ----
        bfrag pf[2][2], vf[4][2];
#pragma unroll
        for (int m = 0; m < 2; ++m)
#pragma unroll
            for (int c = 0; c < 2; ++c)
                pf[m][c] = *(const bfrag*)(&Ps[wrow + m * 16 + lrow][c * 32 + quad * 8]);
#pragma unroll
        for (int n = 0; n < 4; ++n)
#pragma unroll
            for (int c = 0; c < 2; ++c)
                vf[n][c] = *(const bfrag*)(&Vt[n * 16 + lrow][c * 32 + quad * 8]);
#pragma unroll
        for (int m = 0; m < 2; ++m) {
#pragma unroll
            for (int n = 0; n < 4; ++n) {
                oacc[m][n] = __builtin_amdgcn_mfma_f32_16x16x32_bf16(pf[m][0], vf[n][0], oacc[m][n], 0, 0, 0);
                oacc[m][n] = __builtin_amdgcn_mfma_f32_16x16x32_bf16(pf[m][1], vf[n][1], oacc[m][n], 0, 0, 0);
            }
            lacc[m] = __builtin_amdgcn_mfma_f32_16x16x32_bf16(pf[m][0], vOnes, lacc[m], 0, 0, 0);
            lacc[m] = __builtin_amdgcn_mfma_f32_16x16x32_bf16(pf[m][1], vOnes, lacc[m], 0, 0, 0);
        }
    }

    // ---- epilogue: broadcast l (col 0 -> lane lrow==0 of each quad), write o ----
#pragma unroll
    for (int m = 0; m < 2; ++m)
#pragma unroll
        for (int r = 0; r < 4; ++r) {
            float lv = __shfl(lacc[m][r], lane & 48, 64);
            float inv = 1.f / lv;
            int row = b * S_LEN + s0 + wrow + m * 16 + quad * 4 + r;
#pragma unroll
            for (int n = 0; n < 4; ++n)
                o[(size_t)row * 2048 + h * 64 + n * 16 + lrow] = (bf16_t)(oacc[m][n][r] * inv);
        }
}

// ---------------------------------------------------------------------------
extern "C" void kernel_launch(void* const* d_in, const int* in_sizes, int n_in,
                              void* d_out, int out_size, void* d_ws, size_t ws_size,
                              hipStream_t stream)
{
    const float* x    = (const float*)d_in[0];
    const float* rc   = (const float*)d_in[1];
    const float* rs   = (const float*)d_in[2];
    const float* mask = (const float*)d_in[3];
    const float* Wq   = (const float*)d_in[4];
    const float* Wk   = (const float*)d_in[5];
    const float* Wv   = (const float*)d_in[6];
    const float* Wo   = (const float*)d_in[7];
    float* out = (float*)d_out;

    char* ws = (char*)d_ws;
    bf16_t* qkv = (bf16_t*)(ws);                  // [4096][3072] = 24 MiB
    bf16_t* xb  = (bf16_t*)(ws + (24u << 20));    // [4096][2048] = 16 MiB
    bf16_t* ob  = xb;                             // aliases xb (dead after QKV GEMM)
    bf16_t* Wt3 = (bf16_t*)(ws + (40u << 20));    // [3072][2048] = 12 MiB
    bf16_t* Wot = (bf16_t*)(ws + (52u << 20));    // [2048][2048] =  8 MiB

    const int M = 2 * S_LEN;  // 4096
    dim3 blk(256);

    // pre-pass: cvt x, transpose+cvt weights (Wq/Wk/Wv fused into Wt3)
    cvt_bf16<<<(M * 2048) / (256 * 8), blk, 0, stream>>>(x, xb, M * 2048);
    transpose_cvt<<<dim3(64, 64), dim3(32, 8), 0, stream>>>(Wq, Wt3, 2048, 2048, 0);
    transpose_cvt<<<dim3(16, 64), dim3(32, 8), 0, stream>>>(Wk, Wt3, 2048,  512, 2048);
    transpose_cvt<<<dim3(16, 64), dim3(32, 8), 0, stream>>>(Wv, Wt3, 2048,  512, 2560);
    transpose_cvt<<<dim3(64, 64), dim3(32, 8), 0, stream>>>(Wo, Wot, 2048, 2048, 0);

    // fused QKV projection: qkv[4096][3072] bf16
    gemm_bt<true><<<dim3(3072 / 128, M / 128), blk, 0, stream>>>(
        xb, Wt3, qkv, M, 3072, 2048, 3072);

    // RoPE on q (scaled by LOG2E) and k, in place
    rope_fused<<<(M * 1280) / 256, blk, 0, stream>>>(qkv, rc, rs);

    // attention -> ob[4096][2048] bf16
    attn_mfma<<<dim3(16, 32, 2), blk, 0, stream>>>(qkv, mask, ob);

    // out-projection -> fp32
    gemm_bt<false><<<dim3(2048 / 128, M / 128), blk, 0, stream>>>(
        ob, Wot, out, M, 2048, 2048, 2048);
}